// Round 13
// baseline (267.028 us; speedup 1.0000x reference)
//
#include <hip/hip_runtime.h>
#include <math.h>

namespace {
constexpr int NB = 4, NCHT = 29, NF = 19, NM = 7, NHI = 3;
constexpr int HH = 512, WW = 512;
constexpr int PH  = 170;           // pooled H/W (512-3)/3+1
constexpr int NHW = 168;           // shifted-view grid 170-3+1
constexpr int NS  = NHW * NHW;     // 28224 samples
constexpr int NBC = NB * NCHT;     // 116 (b,c) pairs
constexpr int CROWS = 14;          // sample rows per kCov chunk
constexpr int NCH2  = NHW / CROWS; // 12 chunks

constexpr int F2M[NF] = {0,0,0,1,1,1,2,2,3,3,4,5,5,6,6,6,6,6,6};
constexpr int M2H[NM] = {0,0,1,1,1,2,2};
constexpr int F2H[NF] = {0,0,0,0,0,0,1,1,1,1,1,2,2,2,2,2,2,2,2};

constexpr unsigned long long packTbl(const int* a, int n) {
  unsigned long long p = 0;
  for (int i = 0; i < n; i++) p |= (unsigned long long)(a[i]) << (3 * i);
  return p;
}
constexpr unsigned long long PF2M = packTbl(F2M, NF);
constexpr unsigned long long PF2H = packTbl(F2H, NF);

// ws float layout
constexpr int    WS_S1  = 16;     // raw view sums, 116*32
constexpr int    WS_COV = 4096;   // raw upper-tri moments, 116*324
constexpr int    WS_RED = 49152;  // 64 slots * 16 floats (real BCE partials)
constexpr int    WS_DBG = 50176;  // 256 floats dummy sink for ablation kernels
constexpr size_t WS_LA  = 65536;
constexpr size_t WS_PR  = WS_LA + (size_t)NBC * PH * PH;
constexpr size_t WS_ZERO_BYTES = (size_t)(WS_RED + 64 * 16) * 4;
} // namespace

// async global->LDS DMA, 16B per lane; dest must be linear in lane order.
#define GLOAD16(gsrc, ldst)                                                     \
  __builtin_amdgcn_global_load_lds(                                             \
      (const __attribute__((address_space(1))) void*)(gsrc),                    \
      (__attribute__((address_space(3))) void*)(ldst), 16, 0, 0)

// ---------------- kernel A: DMA-staged sigmoid + hierarchy + BCE + pool ------
// (unchanged from R12 — the measured 86-88us baseline)
__global__ __launch_bounds__(192)
void kA(const float* __restrict__ cls, const int* __restrict__ label,
        float* __restrict__ ws) {
  const int bx  = blockIdx.x;
  const int wy  = blockIdx.y;
  const int b   = blockIdx.z;
  const int tid = threadIdx.x;
  const int x0  = 48 * bx;
  const int y0  = 3 * wy;
  const int rmax = (wy == 170) ? 1 : 2;

  const int W4   = (bx < 10) ? 12 : 8;   // float4s per channel-row
  const int NCOL = 4 * W4;               // 48 or 32
  const int CST  = 3 * NCOL;             // floats per channel in LDS (packed)
  const int NW   = (bx < 10) ? 16 : 10;  // pool windows in this block

  __shared__ __align__(16) float    sPixF[NCHT * 144];  // packed [c][3*NCOL]
  __shared__ unsigned sMask[144];
  __shared__ float    sRed[4][3];

  // ---- phase 0: async DMA staging ------------------------------------------
  {
    const int T3 = 3 * W4;
    const int total = NCHT * T3;
    for (int i = tid; i < total; i += 192) {
      const int c   = i / T3;
      const int rem = i - c * T3;
      const int r   = rem / W4;
      const int f   = rem - r * W4;
      const int rr  = (r <= rmax) ? r : rmax;
      const float* src =
          cls + ((size_t)(b * NCHT + c) * HH + (y0 + rr)) * WW + x0 + 4 * f;
      GLOAD16(src, &sPixF[4 * i]);
    }
  }
  __syncthreads();

  // ---- phase 1: one pixel per thread ---------------------------------------
  float bce0 = 0.f, bce1 = 0.f, bce2 = 0.f, cnt = 0.f;
  {
    const int p = tid;
    const int r = p / NCOL;
    if (p < CST && r <= rmax) {
      const int col = p - r * NCOL;
      const int lbl = label[((size_t)b * HH + (y0 + r)) * WW + x0 + col];
      const bool valid = (lbl != 255);
      const int lf = valid ? lbl : 0;
      const int lm = (int)((PF2M >> (3 * lf)) & 7ull);
      const int lh = (int)((PF2H >> (3 * lf)) & 7ull);
      const float vm = valid ? 1.f : 0.f;

      float pv[NCHT];
      #pragma unroll
      for (int c = 0; c < NCHT; c++)
        pv[c] = __builtin_amdgcn_rcpf(1.f + __expf(-sPixF[c * CST + p]));

      float segf[NM];
      #pragma unroll
      for (int m = 0; m < NM; m++) segf[m] = -1.f;
      #pragma unroll
      for (int f = 0; f < NF; f++) segf[F2M[f]] = fmaxf(segf[F2M[f]], pv[f]);
      float pBc[NM];
      #pragma unroll
      for (int m = 0; m < NM; m++) pBc[m] = fmaxf(segf[m], pv[NF + m]);
      float segm[NHI];
      #pragma unroll
      for (int k = 0; k < NHI; k++) segm[k] = -1.f;
      #pragma unroll
      for (int m = 0; m < NM; m++) segm[M2H[m]] = fmaxf(segm[M2H[m]], pBc[m]);
      float pCc[NHI];
      #pragma unroll
      for (int k = 0; k < NHI; k++) pCc[k] = fmaxf(segm[k], pv[NF + NM + k]);

      #pragma unroll
      for (int f = 0; f < NF; f++) {
        const float pos = fminf(pv[f], pv[NF + F2M[f]]);
        if (valid)
          bce0 -= __logf((f == lf) ? pos + 1e-8f : 1.f - pv[f] + 1e-8f);
        sPixF[f * CST + p] = pos * vm + 1e-6f;
      }
      #pragma unroll
      for (int m = 0; m < NM; m++) {
        const float pos = fminf(pv[NF + m], pv[NF + NM + M2H[m]]);
        if (valid)
          bce1 -= __logf((m == lm) ? pos + 1e-8f : 1.f - pBc[m] + 1e-8f);
        sPixF[(NF + m) * CST + p] = pos * vm + 1e-6f;
      }
      #pragma unroll
      for (int k = 0; k < NHI; k++) {
        const float pos = pv[NF + NM + k];
        if (valid)
          bce2 -= __logf((k == lh) ? pos + 1e-8f : 1.f - pCc[k] + 1e-8f);
        sPixF[(NF + NM + k) * CST + p] = pos * vm + 1e-6f;
      }
      sMask[p] = valid ? ((1u << lf) | (1u << (19 + lm)) | (1u << (26 + lh))) : 0u;
      cnt = vm;
    }
  }

  #pragma unroll
  for (int m = 32; m >= 1; m >>= 1) {
    bce0 += __shfl_xor(bce0, m);
    bce1 += __shfl_xor(bce1, m);
    bce2 += __shfl_xor(bce2, m);
    cnt  += __shfl_xor(cnt, m);
  }
  {
    const int wave = tid >> 6, lane = tid & 63;
    if (lane == 0) {
      sRed[0][wave] = bce0; sRed[1][wave] = bce1;
      sRed[2][wave] = bce2; sRed[3][wave] = cnt;
    }
  }
  __syncthreads();

  // ---- phase 2: 3x3 pool from LDS; c-major tasks ---------------------------
  if (wy < 170) {
    float* la = ws + WS_LA;
    float* pr = ws + WS_PR;
    for (int t = tid; t < 16 * NCHT; t += 192) {
      const int c = t >> 4;
      const int w = t & 15;
      if (w < NW) {
        const int c0 = 3 * w;
        unsigned m = 0u;
        #pragma unroll
        for (int r = 0; r < 3; r++)
          m |= sMask[r * NCOL + c0] | sMask[r * NCOL + c0 + 1] |
               sMask[r * NCOL + c0 + 2];
        const size_t base =
            ((size_t)(b * NCHT) * PH + wy) * PH + (16 * bx + w);
        la[base + (size_t)c * PH * PH] = (float)((m >> c) & 1u);
        float v = 0.f;
        #pragma unroll
        for (int r = 0; r < 3; r++)
          v = fmaxf(v, fmaxf(fmaxf(sPixF[c * CST + r * NCOL + c0],
                                   sPixF[c * CST + r * NCOL + c0 + 1]),
                             sPixF[c * CST + r * NCOL + c0 + 2]));
        pr[base + (size_t)c * PH * PH] = v;
      }
    }
  }

  if (tid == 0) {
    const int slot = (bx + 11 * (wy + 171 * b)) & 63;
    float* dst = ws + WS_RED + slot * 16;
    atomicAdd(&dst[0], sRed[0][0] + sRed[0][1] + sRed[0][2]);
    atomicAdd(&dst[1], sRed[1][0] + sRed[1][1] + sRed[1][2]);
    atomicAdd(&dst[2], sRed[2][0] + sRed[2][1] + sRed[2][2]);
    atomicAdd(&dst[3], sRed[3][0] + sRed[3][1] + sRed[3][2]);
  }
}

// ---------------- ABLATION A: staging x3 (T ~ 3S) ----------------------------
// Same geometry/addresses as kA phase 0, repeated 3x. Dummy sink only.
__global__ __launch_bounds__(192)
void kAblStage(const float* __restrict__ cls, float* __restrict__ dbg) {
  const int bx  = blockIdx.x;
  const int wy  = blockIdx.y;
  const int b   = blockIdx.z;
  const int tid = threadIdx.x;
  const int x0  = 48 * bx;
  const int y0  = 3 * wy;
  const int rmax = (wy == 170) ? 1 : 2;
  const int W4   = (bx < 10) ? 12 : 8;

  __shared__ __align__(16) float sPixF[NCHT * 144];

  for (int k = 0; k < 3; k++) {
    const int T3 = 3 * W4;
    const int total = NCHT * T3;
    for (int i = tid; i < total; i += 192) {
      const int c   = i / T3;
      const int rem = i - c * T3;
      const int r   = rem / W4;
      const int f   = rem - r * W4;
      const int rr  = (r <= rmax) ? r : rmax;
      const float* src =
          cls + ((size_t)(b * NCHT + c) * HH + (y0 + rr)) * WW + x0 + 4 * f;
      GLOAD16(src, &sPixF[4 * i]);
    }
    __syncthreads();
  }
  if (tid == 0)
    atomicAdd(&dbg[(bx + 11 * (wy + 171 * b)) & 255], sPixF[0]);
}

// ---------------- ABLATION B: stage x1 + phase-1 compute x3 (T ~ S + 3(L+C)) -
__global__ __launch_bounds__(192)
void kAblComp(const float* __restrict__ cls, const int* __restrict__ label,
              float* __restrict__ dbg) {
  const int bx  = blockIdx.x;
  const int wy  = blockIdx.y;
  const int b   = blockIdx.z;
  const int tid = threadIdx.x;
  const int x0  = 48 * bx;
  const int y0  = 3 * wy;
  const int rmax = (wy == 170) ? 1 : 2;
  const int W4   = (bx < 10) ? 12 : 8;
  const int NCOL = 4 * W4;
  const int CST  = 3 * NCOL;

  __shared__ __align__(16) float sPixF[NCHT * 144];
  __shared__ unsigned sMask[144];

  {
    const int T3 = 3 * W4;
    const int total = NCHT * T3;
    for (int i = tid; i < total; i += 192) {
      const int c   = i / T3;
      const int rem = i - c * T3;
      const int r   = rem / W4;
      const int f   = rem - r * W4;
      const int rr  = (r <= rmax) ? r : rmax;
      const float* src =
          cls + ((size_t)(b * NCHT + c) * HH + (y0 + rr)) * WW + x0 + 4 * f;
      GLOAD16(src, &sPixF[4 * i]);
    }
  }
  __syncthreads();

  float bce0 = 0.f, bce1 = 0.f, bce2 = 0.f, cnt = 0.f;
  for (int it = 0; it < 3; it++) {
    const int p = tid;
    const int r = p / NCOL;
    if (p < CST && r <= rmax) {
      const int col = p - r * NCOL;
      const int lbl = label[((size_t)b * HH + (y0 + r)) * WW + x0 + col];
      const bool valid = (lbl != 255);
      const int lf = valid ? lbl : 0;
      const int lm = (int)((PF2M >> (3 * lf)) & 7ull);
      const int lh = (int)((PF2H >> (3 * lf)) & 7ull);
      const float vm = valid ? 1.f : 0.f;

      float pv[NCHT];
      #pragma unroll
      for (int c = 0; c < NCHT; c++)
        pv[c] = __builtin_amdgcn_rcpf(1.f + __expf(-sPixF[c * CST + p]));

      float segf[NM];
      #pragma unroll
      for (int m = 0; m < NM; m++) segf[m] = -1.f;
      #pragma unroll
      for (int f = 0; f < NF; f++) segf[F2M[f]] = fmaxf(segf[F2M[f]], pv[f]);
      float pBc[NM];
      #pragma unroll
      for (int m = 0; m < NM; m++) pBc[m] = fmaxf(segf[m], pv[NF + m]);
      float segm[NHI];
      #pragma unroll
      for (int k = 0; k < NHI; k++) segm[k] = -1.f;
      #pragma unroll
      for (int m = 0; m < NM; m++) segm[M2H[m]] = fmaxf(segm[M2H[m]], pBc[m]);
      float pCc[NHI];
      #pragma unroll
      for (int k = 0; k < NHI; k++) pCc[k] = fmaxf(segm[k], pv[NF + NM + k]);

      #pragma unroll
      for (int f = 0; f < NF; f++) {
        const float pos = fminf(pv[f], pv[NF + F2M[f]]);
        if (valid)
          bce0 -= __logf((f == lf) ? pos + 1e-8f : 1.f - pv[f] + 1e-8f);
        sPixF[f * CST + p] = pos * vm + 1e-6f;
      }
      #pragma unroll
      for (int m = 0; m < NM; m++) {
        const float pos = fminf(pv[NF + m], pv[NF + NM + M2H[m]]);
        if (valid)
          bce1 -= __logf((m == lm) ? pos + 1e-8f : 1.f - pBc[m] + 1e-8f);
        sPixF[(NF + m) * CST + p] = pos * vm + 1e-6f;
      }
      #pragma unroll
      for (int k = 0; k < NHI; k++) {
        const float pos = pv[NF + NM + k];
        if (valid)
          bce2 -= __logf((k == lh) ? pos + 1e-8f : 1.f - pCc[k] + 1e-8f);
        sPixF[(NF + NM + k) * CST + p] = pos * vm + 1e-6f;
      }
      sMask[p] = valid ? ((1u << lf) | (1u << (19 + lm)) | (1u << (26 + lh))) : 0u;
      cnt += vm;
    }
  }

  #pragma unroll
  for (int m = 32; m >= 1; m >>= 1) {
    bce0 += __shfl_xor(bce0, m);
    bce1 += __shfl_xor(bce1, m);
    bce2 += __shfl_xor(bce2, m);
    cnt  += __shfl_xor(cnt, m);
  }
  if ((tid & 63) == 0) {
    float* dst = &dbg[((bx + 11 * (wy + 171 * b)) & 31) * 8];
    atomicAdd(&dst[0], bce0 + bce1);
    atomicAdd(&dst[1], bce2 + cnt + (float)sMask[tid & 127]);
  }
}

// ---------------- kernel Cov: RAW 18x18 moments + view sums, LDS stencil ----
__global__ __launch_bounds__(192)
void kCov(const float* __restrict__ ws_base, float* __restrict__ cov,
          float* __restrict__ s1out) {
  const int bc    = blockIdx.x / NCH2;
  const int chunk = blockIdx.x % NCH2;
  const int tid   = threadIdx.x;
  const int tile  = tid / 32;
  const int g     = tid % 32;
  const int ta = (tile < 3) ? 0 : ((tile < 5) ? 1 : 2);
  const int tb = (tile < 3) ? tile : ((tile < 5) ? tile - 2 : 2);
  const bool diag = (ta == tb);

  __shared__ __align__(16) float sA[16 * PH];
  __shared__ __align__(16) float sP[16 * PH];

  const int r0 = chunk * CROWS;
  const float* Ag = ws_base + WS_LA + (size_t)bc * PH * PH + (size_t)r0 * PH;
  const float* Pg = ws_base + WS_PR + (size_t)bc * PH * PH + (size_t)r0 * PH;
  for (int i = tid; i < (16 * PH) / 4; i += 192) {
    GLOAD16(Ag + 4 * i, &sA[4 * i]);
    GLOAD16(Pg + 4 * i, &sP[4 * i]);
  }
  __syncthreads();

  const float* baseA[6];
  const float* baseB[6];
  #pragma unroll
  for (int k = 0; k < 6; k++) {
    int r = 6 * ta + k, rr = r % 9;
    baseA[k] = ((r < 9) ? sA : sP) + (rr / 3) * PH + (rr % 3);
    int r2 = 6 * tb + k, rr2 = r2 % 9;
    baseB[k] = ((r2 < 9) ? sA : sP) + (rr2 / 3) * PH + (rr2 % 3);
  }

  float acc[6][6];
  #pragma unroll
  for (int k = 0; k < 6; k++)
    #pragma unroll
    for (int l = 0; l < 6; l++) acc[k][l] = 0.f;
  float sums[6];
  #pragma unroll
  for (int k = 0; k < 6; k++) sums[k] = 0.f;

  for (int lr = 0; lr < CROWS; lr++) {
    const int rowoff = lr * PH;
    for (int lc = g; lc < NHW; lc += 32) {
      float va[6], vb[6];
      #pragma unroll
      for (int k = 0; k < 6; k++) va[k] = baseA[k][rowoff + lc];
      #pragma unroll
      for (int k = 0; k < 6; k++) vb[k] = baseB[k][rowoff + lc];
      #pragma unroll
      for (int k = 0; k < 6; k++)
        #pragma unroll
        for (int l = 0; l < 6; l++) acc[k][l] = fmaf(va[k], vb[l], acc[k][l]);
      if (diag) {
        #pragma unroll
        for (int k = 0; k < 6; k++) sums[k] += va[k];
      }
    }
  }

  #pragma unroll
  for (int k = 0; k < 6; k++)
    #pragma unroll
    for (int l = 0; l < 6; l++) {
      float v = acc[k][l];
      #pragma unroll
      for (int m = 16; m >= 1; m >>= 1) v += __shfl_xor(v, m);
      acc[k][l] = v;
    }
  if (diag) {
    #pragma unroll
    for (int k = 0; k < 6; k++) {
      float v = sums[k];
      #pragma unroll
      for (int m = 16; m >= 1; m >>= 1) v += __shfl_xor(v, m);
      sums[k] = v;
    }
  }
  if (g == 0) {
    float* dst = cov + (size_t)bc * 324;
    #pragma unroll
    for (int k = 0; k < 6; k++)
      #pragma unroll
      for (int l = 0; l < 6; l++)
        atomicAdd(&dst[(6 * ta + k) * 18 + 6 * tb + l], acc[k][l]);
    if (diag) {
      #pragma unroll
      for (int k = 0; k < 6; k++)
        atomicAdd(&s1out[bc * 32 + 6 * ta + k], sums[k]);
    }
  }
}

// ---------------- kernel Solve: one wave per (b,c); center in DOUBLE --------
__global__ __launch_bounds__(64)
void kSolve(const float* __restrict__ cov_all, const float* __restrict__ s1,
            float* __restrict__ acc) {
  const int bc   = blockIdx.x;
  const int lane = threadIdx.x;
  const float* cr = cov_all + (size_t)bc * 324;
  const double n = (double)NS;

  double mu[18];
  #pragma unroll
  for (int r = 0; r < 18; r++) mu[r] = (double)s1[bc * 32 + r] / n;
#define CC(i, j) ((double)cr[(i) * 18 + (j)] - n * mu[(i)] * mu[(j)])

  double row[9];
  #pragma unroll
  for (int j = 0; j < 9; j++)
    row[j] = (lane < 9 && j <= lane) ? CC(9 + j, 9 + lane) : 0.0;
  if (lane < 9) row[lane] += 1e-3;

  #pragma unroll
  for (int k = 0; k < 9; k++) {
    if (lane == k) {
      double s = row[k];
      #pragma unroll
      for (int m = 0; m < k; m++) s -= row[m] * row[m];
      row[k] = sqrt(fmax(s, 1e-300));
    }
    double rk[9];
    #pragma unroll
    for (int m = 0; m <= k; m++) rk[m] = __shfl(row[m], k);
    if (lane > k && lane < 9) {
      double s = row[k];
      #pragma unroll
      for (int m = 0; m < k; m++) s -= row[m] * rk[m];
      row[k] = s / rk[k];
    }
  }

  double Lm[9][9];
  #pragma unroll
  for (int i = 0; i < 9; i++)
    #pragma unroll
    for (int m = 0; m <= i; m++) Lm[i][m] = __shfl(row[m], i);

  double mc[9];
  #pragma unroll
  for (int r = 0; r < 9; r++) mc[r] = 0.0;
  if (lane < 9) {
    #pragma unroll
    for (int r = 0; r < 9; r++) {
      double s = CC(lane, 9 + r);
      #pragma unroll
      for (int m = 0; m < r; m++) s -= Lm[r][m] * mc[m];
      mc[r] = s / Lm[r][r];
    }
  }

  double a2[9];
  #pragma unroll
  for (int j = 0; j < 9; j++) a2[j] = 0.0;
  #pragma unroll
  for (int j = 0; j < 9; j++) {
    double mj[9];
    #pragma unroll
    for (int r = 0; r < 9; r++) mj[r] = __shfl(mc[r], j);
    double dot = 0.0;
    #pragma unroll
    for (int r = 0; r < 9; r++) dot += mc[r] * mj[r];
    if (lane < 9 && j <= lane)
      a2[j] = CC(j, lane) - dot + ((j == lane) ? 1e-3 : 0.0);
  }
#undef CC

  double myld = 0.0;
  #pragma unroll
  for (int k = 0; k < 9; k++) {
    if (lane == k) {
      double s = a2[k];
      #pragma unroll
      for (int m = 0; m < k; m++) s -= a2[m] * a2[m];
      double d = sqrt(fmax(s, 0.0));
      a2[k] = d;
      myld = 2.0 * log(d + 1e-8);
    }
    double rk[9];
    #pragma unroll
    for (int m = 0; m <= k; m++) rk[m] = __shfl(a2[m], k);
    if (lane > k && lane < 9) {
      double s = a2[k];
      #pragma unroll
      for (int m = 0; m < k; m++) s -= a2[m] * rk[m];
      a2[k] = s / rk[k];
    }
  }
  #pragma unroll
  for (int m = 32; m >= 1; m >>= 1) myld += __shfl_xor(myld, m);
  if (lane == 0) atomicAdd(&acc[4], (float)myld);
}

// ---------------- finalize: reduce 64 BCE slots + combine --------------------
__global__ void kFin(const float* __restrict__ ws, float* __restrict__ out) {
  const int tid = threadIdx.x;
  const float* slot = ws + WS_RED + tid * 16;
  float b0 = slot[0], b1 = slot[1], b2 = slot[2], b3 = slot[3];
  #pragma unroll
  for (int m = 32; m >= 1; m >>= 1) {
    b0 += __shfl_xor(b0, m);
    b1 += __shfl_xor(b1, m);
    b2 += __shfl_xor(b2, m);
    b3 += __shfl_xor(b3, m);
  }
  if (tid == 0) {
    const double cnt = (double)b3;
    const double bce = 0.5 * ((double)b0 / (cnt * NF + 1e-8) +
                              (double)b1 / (cnt * NM + 1e-8) +
                              (double)b2 / (cnt * NHI + 1e-8));
    const double rmi = 0.5 * (double)ws[4] / (double)(NB * 9);
    out[0] = (float)(bce + rmi);
  }
}

extern "C" void kernel_launch(void* const* d_in, const int* in_sizes, int n_in,
                              void* d_out, int out_size, void* d_ws, size_t ws_size,
                              hipStream_t stream) {
  (void)in_sizes; (void)n_in; (void)out_size; (void)ws_size;
  const float* cls   = (const float*)d_in[3];
  const int*   label = (const int*)d_in[4];
  float* ws = (float*)d_ws;

  hipMemsetAsync(d_ws, 0, WS_ZERO_BYTES, stream);

  dim3 gA(11, 171, NB);
  kA<<<gA, 192, 0, stream>>>(cls, label, ws);
  kCov<<<NBC * NCH2, 192, 0, stream>>>(ws, ws + WS_COV, ws + WS_S1);
  kSolve<<<NBC, 64, 0, stream>>>(ws + WS_COV, ws + WS_S1, ws);
  kFin<<<1, 64, 0, stream>>>(ws, (float*)d_out);

  // ---- diagnostic ablations (dummy sink; durations read from rocprof) ------
  kAblStage<<<gA, 192, 0, stream>>>(cls, ws + WS_DBG);
  kAblComp<<<gA, 192, 0, stream>>>(cls, label, ws + WS_DBG);
}

// Round 14
// 116.984 us; speedup vs baseline: 2.2826x; 2.2826x over previous
//
#include <hip/hip_runtime.h>
#include <math.h>

namespace {
constexpr int NB = 4, NCHT = 29, NF = 19, NM = 7, NHI = 3;
constexpr int HH = 512, WW = 512;
constexpr int PH  = 170;           // pooled H/W
constexpr int NHW = 168;           // shifted-view grid
constexpr int NS  = NHW * NHW;     // 28224 samples
constexpr int NBC = NB * NCHT;     // 116
constexpr int CROWS = 14;
constexpr int NCH2  = NHW / CROWS; // 12
constexpr int LDSW  = 176;         // padded LDS row (11 tiles * 16)

constexpr int F2M[NF] = {0,0,0,1,1,1,2,2,3,3,4,5,5,6,6,6,6,6,6};
constexpr int M2H[NM] = {0,0,1,1,1,2,2};

constexpr unsigned long long packTbl(const int* a, int n) {
  unsigned long long p = 0;
  for (int i = 0; i < n; i++) p |= (unsigned long long)(a[i]) << (3 * i);
  return p;
}
constexpr int F2H_[NF] = {0,0,0,0,0,0,1,1,1,1,1,2,2,2,2,2,2,2,2};
constexpr unsigned long long PF2M = packTbl(F2M, NF);
constexpr unsigned long long PF2H = packTbl(F2H_, NF);

// ws float layout
constexpr int    WS_S1  = 16;       // raw view sums, 116*32
constexpr int    WS_COV = 4096;     // raw upper-tri moments, 116*324
constexpr int    WS_RED = 49152;    // 64 slots * 16 floats
// POOL planes, tiled layout [wy][bxt][bc][w16]: idx = (wy*11+bxt)*1856 + bc*16 + w
constexpr size_t PLANEF = (size_t)170 * 11 * NBC * 16;   // 3,470,720 floats
constexpr size_t WS_LA  = 65536;
constexpr size_t WS_PR  = WS_LA + PLANEF;
constexpr size_t WS_ZERO_BYTES = (size_t)(WS_RED + 64 * 16) * 4;
} // namespace

// async global->LDS DMA, 16B per lane; LDS dest linear in lane order,
// GLOBAL source per-lane (m104).
#define GLOAD16(gsrc, ldst)                                                     \
  __builtin_amdgcn_global_load_lds(                                             \
      (const __attribute__((address_space(1))) void*)(gsrc),                    \
      (__attribute__((address_space(3))) void*)(ldst), 16, 0, 0)

// ---------------- kernel A: logit-space hierarchy + BCE + pool ---------------
// grid (11, 171, NB), 192 thr. bx<10: 48 cols (16 windows); bx=10: 32 cols.
// R13 ablation: compute VALU-bound (89% busy at x3), stage/pool each ~25-35us.
// R14: (a) x-space hierarchy & pooling (sigmoid monotone), BCE via
// log-products of (1+e^arg): 29exp+4log vs 29exp+29rcp+29log; (b) POOL tiled
// layout -> block's la/pr writes are ONE contiguous 1856B run each;
// (c) template<W4> -> compile-time divisors in staging.
template <int W4>
__device__ __forceinline__ void kA_body(
    const int bx, const int wy, const int b, const int tid,
    const float* __restrict__ cls, const int* __restrict__ label,
    float* __restrict__ ws, float* sPixF, unsigned* sMask, float (*sRed)[3]) {
  constexpr int NCOL = 4 * W4;       // 48 or 32
  constexpr int CST  = 3 * NCOL;     // 144 or 96
  constexpr int T3   = 3 * W4;
  const int x0   = 48 * bx;
  const int y0   = 3 * wy;
  const int rmax = (wy == 170) ? 1 : 2;

  // ---- phase 0: async DMA staging (compile-time divisors) ------------------
  for (int i = tid; i < NCHT * T3; i += 192) {
    const int c   = i / T3;
    const int rem = i - c * T3;
    const int r   = rem / W4;
    const int f   = rem - r * W4;
    const int rr  = (r <= rmax) ? r : rmax;
    const float* src =
        cls + ((size_t)(b * NCHT + c) * HH + (y0 + rr)) * WW + x0 + 4 * f;
    GLOAD16(src, &sPixF[4 * i]);
  }
  __syncthreads();

  // ---- phase 1: one pixel per thread, all in logit space -------------------
  float bce0 = 0.f, bce1 = 0.f, bce2 = 0.f, cnt = 0.f;
  if (tid < CST) {
    const int r = tid / NCOL;
    if (r <= rmax) {
      const int col = tid - r * NCOL;
      const int lbl = label[((size_t)b * HH + (y0 + r)) * WW + x0 + col];
      const bool valid = (lbl != 255);
      const int lf = valid ? lbl : 0;
      const int lm = (int)((PF2M >> (3 * lf)) & 7ull);
      const int lh = (int)((PF2H >> (3 * lf)) & 7ull);
      const float vm = valid ? 1.f : 0.f;

      float x[NCHT];
      #pragma unroll
      for (int c = 0; c < NCHT; c++) x[c] = sPixF[c * CST + tid];

      // hierarchy maxes in x-space (sigmoid monotone)
      float segf[NM];
      #pragma unroll
      for (int m = 0; m < NM; m++) segf[m] = -1e30f;
      #pragma unroll
      for (int f = 0; f < NF; f++) segf[F2M[f]] = fmaxf(segf[F2M[f]], x[f]);
      float pBx[NM];
      #pragma unroll
      for (int m = 0; m < NM; m++) pBx[m] = fmaxf(segf[m], x[NF + m]);
      float segm[NHI];
      #pragma unroll
      for (int k = 0; k < NHI; k++) segm[k] = -1e30f;
      #pragma unroll
      for (int m = 0; m < NM; m++) segm[M2H[m]] = fmaxf(segm[M2H[m]], pBx[m]);
      float pCx[NHI];
      #pragma unroll
      for (int k = 0; k < NHI; k++) pCx[k] = fmaxf(segm[k], x[NF + NM + k]);

      // BCE: -log(sigmoid(m)) = softplus(-m); -log(1-sigmoid(a)) = softplus(a)
      // sum of softplus == log of product of (1 + e^arg); invalid -> term 1.
      float prA = 1.f, prB = 1.f, prM = 1.f, prH = 1.f;
      #pragma unroll
      for (int f = 0; f < NF; f++) {
        const float mx  = fminf(x[f], x[NF + F2M[f]]);     // pos in x-space
        const float arg = (f == lf) ? -mx : x[f];
        const float t = __builtin_fmaf(vm, __expf(arg), 1.f);
        if (f < 10) prA *= t; else prB *= t;
        sPixF[f * CST + tid] = valid ? mx : -1e30f;
      }
      #pragma unroll
      for (int m = 0; m < NM; m++) {
        const float mx  = fminf(x[NF + m], x[NF + NM + M2H[m]]);
        const float arg = (m == lm) ? -mx : pBx[m];
        prM *= __builtin_fmaf(vm, __expf(arg), 1.f);
        sPixF[(NF + m) * CST + tid] = valid ? mx : -1e30f;
      }
      #pragma unroll
      for (int k = 0; k < NHI; k++) {
        const float px  = x[NF + NM + k];
        const float arg = (k == lh) ? -px : pCx[k];
        prH *= __builtin_fmaf(vm, __expf(arg), 1.f);
        sPixF[(NF + NM + k) * CST + tid] = valid ? px : -1e30f;
      }
      bce0 = __logf(prA) + __logf(prB);
      bce1 = __logf(prM);
      bce2 = __logf(prH);
      sMask[tid] = valid ? ((1u << lf) | (1u << (19 + lm)) | (1u << (26 + lh))) : 0u;
      cnt = vm;
    }
  }

  #pragma unroll
  for (int m = 32; m >= 1; m >>= 1) {
    bce0 += __shfl_xor(bce0, m);
    bce1 += __shfl_xor(bce1, m);
    bce2 += __shfl_xor(bce2, m);
    cnt  += __shfl_xor(cnt, m);
  }
  {
    const int wave = tid >> 6, lane = tid & 63;
    if (lane == 0) {
      sRed[0][wave] = bce0; sRed[1][wave] = bce1;
      sRed[2][wave] = bce2; sRed[3][wave] = cnt;
    }
  }
  __syncthreads();

  // ---- phase 2: pool in x-space, sigmoid once; contiguous tiled stores -----
  if (wy < 170) {
    const size_t base = (size_t)(wy * 11 + bx) * 1856 + (size_t)b * 464;
    float* la = ws + WS_LA + base;
    float* pr = ws + WS_PR + base;
    for (int t = tid; t < 464; t += 192) {
      const int c = t >> 4, w = t & 15;
      const int c0 = 3 * w;
      unsigned m = 0u;
      #pragma unroll
      for (int r = 0; r < 3; r++)
        m |= sMask[r * NCOL + c0] | sMask[r * NCOL + c0 + 1] |
             sMask[r * NCOL + c0 + 2];
      la[t] = (float)((m >> c) & 1u);
      float v = -1e30f;
      #pragma unroll
      for (int r = 0; r < 3; r++)
        v = fmaxf(v, fmaxf(fmaxf(sPixF[c * CST + r * NCOL + c0],
                                 sPixF[c * CST + r * NCOL + c0 + 1]),
                           sPixF[c * CST + r * NCOL + c0 + 2]));
      // all-invalid window: v=-1e30 -> exp(+1e30)=inf -> rcp(inf)=0 -> 1e-6
      pr[t] = __builtin_amdgcn_rcpf(1.f + __expf(-v)) + 1e-6f;
    }
  }

  if (tid == 0) {
    const int slot = (bx + 11 * (wy + 171 * b)) & 63;
    float* dst = ws + WS_RED + slot * 16;
    atomicAdd(&dst[0], sRed[0][0] + sRed[0][1] + sRed[0][2]);
    atomicAdd(&dst[1], sRed[1][0] + sRed[1][1] + sRed[1][2]);
    atomicAdd(&dst[2], sRed[2][0] + sRed[2][1] + sRed[2][2]);
    atomicAdd(&dst[3], sRed[3][0] + sRed[3][1] + sRed[3][2]);
  }
}

__global__ __launch_bounds__(192)
void kA(const float* __restrict__ cls, const int* __restrict__ label,
        float* __restrict__ ws) {
  __shared__ __align__(16) float sPixF[NCHT * 144];
  __shared__ unsigned sMask[144];
  __shared__ float    sRed[4][3];
  const int bx = blockIdx.x, wy = blockIdx.y, b = blockIdx.z;
  if (bx < 10)
    kA_body<12>(bx, wy, b, threadIdx.x, cls, label, ws, sPixF, sMask, sRed);
  else
    kA_body<8>(bx, wy, b, threadIdx.x, cls, label, ws, sPixF, sMask, sRed);
}

// ---------------- kernel Cov: RAW 18x18 moments + view sums, LDS stencil ----
// POOL tiled layout gather: src((wy,wx),bc) = (wy*11+(wx>>4))*1856+bc*16+(wx&15)
__global__ __launch_bounds__(192)
void kCov(const float* __restrict__ ws_base, float* __restrict__ cov,
          float* __restrict__ s1out) {
  const int bc    = blockIdx.x / NCH2;
  const int chunk = blockIdx.x % NCH2;
  const int tid   = threadIdx.x;
  const int tile  = tid / 32;
  const int g     = tid % 32;
  // tiles: 0:(0,0) 1:(0,1) 2:(0,2) 3:(1,1) 4:(1,2) 5:(2,2)
  const int ta = (tile < 3) ? 0 : ((tile < 5) ? 1 : 2);
  const int tb = (tile < 3) ? tile : ((tile < 5) ? tile - 2 : 2);
  const bool diag = (ta == tb);

  __shared__ __align__(16) float sA[16 * LDSW];
  __shared__ __align__(16) float sP[16 * LDSW];

  const int r0 = chunk * CROWS;
  const float* laG = ws_base + WS_LA;
  const float* prG = ws_base + WS_PR;
  for (int i = tid; i < 16 * 44; i += 192) {   // 44 chunks of 4 floats per row
    const int r  = i / 44;
    const int ch = i - 44 * r;
    const int wx = 4 * ch;
    const size_t src =
        (size_t)((r0 + r) * 11 + (wx >> 4)) * 1856 + (size_t)bc * 16 + (wx & 15);
    GLOAD16(laG + src, &sA[4 * i]);
    GLOAD16(prG + src, &sP[4 * i]);
  }
  __syncthreads();

  const float* baseA[6];
  const float* baseB[6];
  #pragma unroll
  for (int k = 0; k < 6; k++) {
    int r = 6 * ta + k, rr = r % 9;
    baseA[k] = ((r < 9) ? sA : sP) + (rr / 3) * LDSW + (rr % 3);
    int r2 = 6 * tb + k, rr2 = r2 % 9;
    baseB[k] = ((r2 < 9) ? sA : sP) + (rr2 / 3) * LDSW + (rr2 % 3);
  }

  float acc[6][6];
  #pragma unroll
  for (int k = 0; k < 6; k++)
    #pragma unroll
    for (int l = 0; l < 6; l++) acc[k][l] = 0.f;
  float sums[6];
  #pragma unroll
  for (int k = 0; k < 6; k++) sums[k] = 0.f;

  for (int lr = 0; lr < CROWS; lr++) {
    const int rowoff = lr * LDSW;
    for (int lc = g; lc < NHW; lc += 32) {
      float va[6], vb[6];
      #pragma unroll
      for (int k = 0; k < 6; k++) va[k] = baseA[k][rowoff + lc];
      #pragma unroll
      for (int k = 0; k < 6; k++) vb[k] = baseB[k][rowoff + lc];
      #pragma unroll
      for (int k = 0; k < 6; k++)
        #pragma unroll
        for (int l = 0; l < 6; l++) acc[k][l] = fmaf(va[k], vb[l], acc[k][l]);
      if (diag) {
        #pragma unroll
        for (int k = 0; k < 6; k++) sums[k] += va[k];
      }
    }
  }

  #pragma unroll
  for (int k = 0; k < 6; k++)
    #pragma unroll
    for (int l = 0; l < 6; l++) {
      float v = acc[k][l];
      #pragma unroll
      for (int m = 16; m >= 1; m >>= 1) v += __shfl_xor(v, m);
      acc[k][l] = v;
    }
  if (diag) {
    #pragma unroll
    for (int k = 0; k < 6; k++) {
      float v = sums[k];
      #pragma unroll
      for (int m = 16; m >= 1; m >>= 1) v += __shfl_xor(v, m);
      sums[k] = v;
    }
  }
  if (g == 0) {
    float* dst = cov + (size_t)bc * 324;
    #pragma unroll
    for (int k = 0; k < 6; k++)
      #pragma unroll
      for (int l = 0; l < 6; l++)
        atomicAdd(&dst[(6 * ta + k) * 18 + 6 * tb + l], acc[k][l]);
    if (diag) {
      #pragma unroll
      for (int k = 0; k < 6; k++)
        atomicAdd(&s1out[bc * 32 + 6 * ta + k], sums[k]);
    }
  }
}

// ---------------- kernel Solve: one wave per (b,c); center in DOUBLE --------
__global__ __launch_bounds__(64)
void kSolve(const float* __restrict__ cov_all, const float* __restrict__ s1,
            float* __restrict__ acc) {
  const int bc   = blockIdx.x;
  const int lane = threadIdx.x;
  const float* cr = cov_all + (size_t)bc * 324;
  const double n = (double)NS;

  double mu[18];
  #pragma unroll
  for (int r = 0; r < 18; r++) mu[r] = (double)s1[bc * 32 + r] / n;
#define CC(i, j) ((double)cr[(i) * 18 + (j)] - n * mu[(i)] * mu[(j)])

  double row[9];
  #pragma unroll
  for (int j = 0; j < 9; j++)
    row[j] = (lane < 9 && j <= lane) ? CC(9 + j, 9 + lane) : 0.0;
  if (lane < 9) row[lane] += 1e-3;

  #pragma unroll
  for (int k = 0; k < 9; k++) {
    if (lane == k) {
      double s = row[k];
      #pragma unroll
      for (int m = 0; m < k; m++) s -= row[m] * row[m];
      row[k] = sqrt(fmax(s, 1e-300));
    }
    double rk[9];
    #pragma unroll
    for (int m = 0; m <= k; m++) rk[m] = __shfl(row[m], k);
    if (lane > k && lane < 9) {
      double s = row[k];
      #pragma unroll
      for (int m = 0; m < k; m++) s -= row[m] * rk[m];
      row[k] = s / rk[k];
    }
  }

  double Lm[9][9];
  #pragma unroll
  for (int i = 0; i < 9; i++)
    #pragma unroll
    for (int m = 0; m <= i; m++) Lm[i][m] = __shfl(row[m], i);

  double mc[9];
  #pragma unroll
  for (int r = 0; r < 9; r++) mc[r] = 0.0;
  if (lane < 9) {
    #pragma unroll
    for (int r = 0; r < 9; r++) {
      double s = CC(lane, 9 + r);
      #pragma unroll
      for (int m = 0; m < r; m++) s -= Lm[r][m] * mc[m];
      mc[r] = s / Lm[r][r];
    }
  }

  double a2[9];
  #pragma unroll
  for (int j = 0; j < 9; j++) a2[j] = 0.0;
  #pragma unroll
  for (int j = 0; j < 9; j++) {
    double mj[9];
    #pragma unroll
    for (int r = 0; r < 9; r++) mj[r] = __shfl(mc[r], j);
    double dot = 0.0;
    #pragma unroll
    for (int r = 0; r < 9; r++) dot += mc[r] * mj[r];
    if (lane < 9 && j <= lane)
      a2[j] = CC(j, lane) - dot + ((j == lane) ? 1e-3 : 0.0);
  }
#undef CC

  double myld = 0.0;
  #pragma unroll
  for (int k = 0; k < 9; k++) {
    if (lane == k) {
      double s = a2[k];
      #pragma unroll
      for (int m = 0; m < k; m++) s -= a2[m] * a2[m];
      double d = sqrt(fmax(s, 0.0));
      a2[k] = d;
      myld = 2.0 * log(d + 1e-8);
    }
    double rk[9];
    #pragma unroll
    for (int m = 0; m <= k; m++) rk[m] = __shfl(a2[m], k);
    if (lane > k && lane < 9) {
      double s = a2[k];
      #pragma unroll
      for (int m = 0; m < k; m++) s -= a2[m] * rk[m];
      a2[k] = s / rk[k];
    }
  }
  #pragma unroll
  for (int m = 32; m >= 1; m >>= 1) myld += __shfl_xor(myld, m);
  if (lane == 0) atomicAdd(&acc[4], (float)myld);
}

// ---------------- finalize: reduce 64 BCE slots + combine --------------------
__global__ void kFin(const float* __restrict__ ws, float* __restrict__ out) {
  const int tid = threadIdx.x;
  const float* slot = ws + WS_RED + tid * 16;
  float b0 = slot[0], b1 = slot[1], b2 = slot[2], b3 = slot[3];
  #pragma unroll
  for (int m = 32; m >= 1; m >>= 1) {
    b0 += __shfl_xor(b0, m);
    b1 += __shfl_xor(b1, m);
    b2 += __shfl_xor(b2, m);
    b3 += __shfl_xor(b3, m);
  }
  if (tid == 0) {
    const double cnt = (double)b3;
    const double bce = 0.5 * ((double)b0 / (cnt * NF + 1e-8) +
                              (double)b1 / (cnt * NM + 1e-8) +
                              (double)b2 / (cnt * NHI + 1e-8));
    const double rmi = 0.5 * (double)ws[4] / (double)(NB * 9);
    out[0] = (float)(bce + rmi);
  }
}

extern "C" void kernel_launch(void* const* d_in, const int* in_sizes, int n_in,
                              void* d_out, int out_size, void* d_ws, size_t ws_size,
                              hipStream_t stream) {
  (void)in_sizes; (void)n_in; (void)out_size; (void)ws_size;
  const float* cls   = (const float*)d_in[3];
  const int*   label = (const int*)d_in[4];
  float* ws = (float*)d_ws;

  hipMemsetAsync(d_ws, 0, WS_ZERO_BYTES, stream);

  dim3 gA(11, 171, NB);
  kA<<<gA, 192, 0, stream>>>(cls, label, ws);
  kCov<<<NBC * NCH2, 192, 0, stream>>>(ws, ws + WS_COV, ws + WS_S1);
  kSolve<<<NBC, 64, 0, stream>>>(ws + WS_COV, ws + WS_S1, ws);
  kFin<<<1, 64, 0, stream>>>(ws, (float*)d_out);
}